// Round 13
// baseline (291.089 us; speedup 1.0000x reference)
//
#include <hip/hip_runtime.h>
#include <hip/hip_bf16.h>
#include <math.h>

#define BB 4
#define SS 512
#define DD 768
#define II 64
#define LL 2
#define HH 12
#define FF 3072
#define MEGA_NB 192

using short8 = __attribute__((ext_vector_type(8))) short;
using f32x4  = __attribute__((ext_vector_type(4))) float;

__device__ __forceinline__ unsigned short f2bf(float x) {
  return __builtin_bit_cast(unsigned short, __float2bfloat16(x));
}

__device__ __forceinline__ void gload_lds16(const void* g, void* l) {
  __builtin_amdgcn_global_load_lds((const __attribute__((address_space(1))) unsigned int*)g,
                                   (__attribute__((address_space(3))) unsigned int*)l, 16, 0, 0);
}

// device-scope grid barrier (all blocks co-resident by construction: 192 blocks, 32KB LDS)
__device__ __forceinline__ void gbar(unsigned* cnt, unsigned nb) {
  __syncthreads();
  if (threadIdx.x == 0) {
    __threadfence();  // agent-scope release of prior writes
    __hip_atomic_fetch_add(cnt, 1u, __ATOMIC_RELAXED, __HIP_MEMORY_SCOPE_AGENT);
    while (__hip_atomic_load(cnt, __ATOMIC_RELAXED, __HIP_MEMORY_SCOPE_AGENT) < nb)
      __builtin_amdgcn_s_sleep(2);
    __threadfence();  // agent-scope acquire
  }
  __syncthreads();
}

struct TC { const float* s[6]; };
struct GB { const unsigned short* A; const unsigned short* Bt; const float* bias; void* C;
            int M; int N; int rowbias; };

// ---------------- prep1: tcast (0..1727) | hs cast (1728..3263) | mask prep (3264..3519) ----------------
__global__ __launch_bounds__(256) void prep1_kernel(
    TC src, unsigned short* __restrict__ WT4, unsigned short* __restrict__ W1T,
    unsigned short* __restrict__ W2T,
    const float* __restrict__ hs0, const float* __restrict__ hs1,
    unsigned short* __restrict__ hsb0, unsigned short* __restrict__ hsb1,
    const int* __restrict__ mask, int* __restrict__ zi,
    unsigned long long* __restrict__ pmask, unsigned char* __restrict__ emask) {
  __shared__ float smem[8192];
  int id = blockIdx.x, t = threadIdx.x;
  if (id < 1728) {
    const float* Ws; unsigned short* WTs; int K, N, k0, n0;
    if (id < 576) {
      int z = id / 72, rem = id - z * 72;
      int widx = z >> 1, l = z & 1;
      Ws = src.s[widx] + (size_t)l * DD * DD;
      WTs = WT4 + ((size_t)widx * 2 + l) * DD * DD;
      K = DD; N = DD; k0 = (rem / 6) * 64; n0 = (rem % 6) * 128;
    } else if (id < 1152) {
      int j = id - 576, l = j / 288, rem = j - l * 288;
      Ws = src.s[4] + (size_t)l * DD * FF;
      WTs = W1T + (size_t)l * FF * DD;
      K = DD; N = FF; k0 = (rem / 24) * 64; n0 = (rem % 24) * 128;
    } else {
      int j = id - 1152, l = j / 288, rem = j - l * 288;
      Ws = src.s[5] + (size_t)l * FF * DD;
      WTs = W2T + (size_t)l * DD * FF;
      K = FF; N = DD; k0 = (rem / 6) * 64; n0 = (rem % 6) * 128;
    }
    int w = t >> 6, lane = t & 63;
    #pragma unroll
    for (int cc = 0; cc < 8; ++cc) {
      int c = w * 8 + cc;
      int row = c * 2 + (lane >> 5);
      int cbyte = (lane & 31) * 16;
      int scb = cbyte ^ ((row & 7) << 4);
      gload_lds16((const char*)(Ws + (size_t)(k0 + row) * N + n0) + scb, (char*)smem + c * 1024);
    }
    __syncthreads();
    int n = t >> 1, kh = t & 1;
    union { unsigned short u[32]; uint4 v4[4]; } pk;
    #pragma unroll
    for (int i = 0; i < 32; ++i) {
      int kl = kh * 32 + i;
      float f = *(const float*)((const char*)smem + kl * 512 + ((n * 4) ^ ((kl & 7) << 4)));
      pk.u[i] = f2bf(f);
    }
    uint4* dst = (uint4*)(WTs + (size_t)(n0 + n) * K + k0 + kh * 32);
    dst[0] = pk.v4[0]; dst[1] = pk.v4[1]; dst[2] = pk.v4[2]; dst[3] = pk.v4[3];
  } else if (id < 3264) {
    int idx = (id - 1728) * 256 + t;
    float4 va = ((const float4*)hs0)[idx];
    float4 vb = ((const float4*)hs1)[idx];
    union { unsigned short u[4]; uint2 v; } pa, pb;
    pa.u[0] = f2bf(va.x); pa.u[1] = f2bf(va.y); pa.u[2] = f2bf(va.z); pa.u[3] = f2bf(va.w);
    pb.u[0] = f2bf(vb.x); pb.u[1] = f2bf(vb.y); pb.u[2] = f2bf(vb.z); pb.u[3] = f2bf(vb.w);
    ((uint2*)hsb0)[idx] = pa.v;
    ((uint2*)hsb1)[idx] = pb.v;
  } else {
    int bi = id - 3264;
    int w = t >> 6;
    const int* mrow = mask + (size_t)bi * SS;
    int m0v = mrow[t], m1v = mrow[t + 256];
    int incl = (m0v == 0) | (m1v == 0);
    int any = __syncthreads_or(incl);
    int z = !any;
    unsigned long long w0 = __ballot(z || (m0v == 0));
    unsigned long long w1 = __ballot(z || (m1v == 0));
    if ((t & 63) == 0) {
      pmask[bi * 8 + w] = w0;
      pmask[bi * 8 + 4 + w] = w1;
      if (t == 0) zi[bi] = z;
    }
    emask[(size_t)bi * SS + t] = (unsigned char)((!z) & (m0v != 0));
    emask[(size_t)bi * SS + t + 256] = (unsigned char)((!z) & (m1v != 0));
  }
}

// ---------------- pooling: 768 blocks, branchless, emask-driven (2KB LDS, high TLP) ----------------
__global__ __launch_bounds__(256) void pool3_kernel(const float* __restrict__ hs0,
                                                    const unsigned char* __restrict__ emask,
                                                    float* __restrict__ qf,
                                                    unsigned short* __restrict__ qb) {
  __shared__ float eadd[SS];
  int bi = blockIdx.x, dz = blockIdx.y;
  int b = bi >> 6, t = threadIdx.x;
  if (t < 128) {
    uchar4 e4 = ((const uchar4*)(emask + (size_t)bi * SS))[t];
    const float NEG = -__builtin_inff();
    eadd[t * 4 + 0] = e4.x ? NEG : 0.0f;
    eadd[t * 4 + 1] = e4.y ? NEG : 0.0f;
    eadd[t * 4 + 2] = e4.z ? NEG : 0.0f;
    eadd[t * 4 + 3] = e4.w ? NEG : 0.0f;
  }
  __syncthreads();
  const float* hb = hs0 + (size_t)b * SS * DD + dz * 256 + t;
  float m[8];
  #pragma unroll
  for (int j = 0; j < 8; ++j) m[j] = -3.4e38f;
  for (int s0 = 0; s0 < SS; s0 += 8) {
    #pragma unroll
    for (int j = 0; j < 8; ++j)
      m[j] = fmaxf(m[j], hb[(size_t)(s0 + j) * DD] + eadd[s0 + j]);
  }
  float mm = fmaxf(fmaxf(fmaxf(m[0], m[1]), fmaxf(m[2], m[3])),
                   fmaxf(fmaxf(m[4], m[5]), fmaxf(m[6], m[7])));
  size_t o = (size_t)bi * DD + dz * 256 + t;
  qf[o] = mm;
  qb[o] = f2bf(mm);
}

// ---------------- NT GEMM 128x128, dbuf 2-phase (4 problems via z) ----------------
template <int GELU, int OUTBF>
__global__ __launch_bounds__(256) void gemm_nt(GB g0, GB g1, GB g2, GB g3, int K) {
  __shared__ unsigned short Al[2][128 * 64];
  __shared__ unsigned short Bl[2][128 * 64];
  GB g = (blockIdx.z == 0) ? g0 : (blockIdx.z == 1) ? g1 : (blockIdx.z == 2) ? g2 : g3;
  int bm = blockIdx.x, bn = blockIdx.y;
  if (blockIdx.z & 1) { bm = blockIdx.y; bn = blockIdx.x; }
  if (bm * 128 >= g.M) return;
  int t = threadIdx.x, w = t >> 6, lane = t & 63;
  int hi = lane >> 4, lo = lane & 15;
  int wr = w >> 1, wc = w & 1;
  f32x4 acc[4][4] = {};
  const char* Abase = (const char*)g.A + (size_t)(bm * 128) * (size_t)K * 2;
  const char* Bbase = (const char*)g.Bt + (size_t)(bn * 128) * (size_t)K * 2;
  int rowbytes = K * 2;
  int KT = K >> 6;
  auto STAGE = [&](int buf, int kt) {
    int k0b = kt * 128;
    #pragma unroll
    for (int c = 0; c < 4; ++c) {
      int base = (c * 4 + w) << 10;
      int o = base + lane * 16;
      int row = o >> 7, cb = o & 127;
      int scb = cb ^ ((row & 7) << 4);
      gload_lds16(Abase + (size_t)row * rowbytes + (k0b + scb), (char*)Al[buf] + base);
      gload_lds16(Bbase + (size_t)row * rowbytes + (k0b + scb), (char*)Bl[buf] + base);
    }
  };
  STAGE(0, 0);
  asm volatile("s_waitcnt vmcnt(0)" ::: "memory");
  __builtin_amdgcn_s_barrier();
  int cur = 0;
  for (int kt = 0; kt < KT; ++kt) {
    if (kt + 1 < KT) STAGE(cur ^ 1, kt + 1);
    #pragma unroll
    for (int kk = 0; kk < 2; ++kk) {
      short8 av[4], bv_[4];
      #pragma unroll
      for (int mi = 0; mi < 4; ++mi) {
        int r = wr * 64 + mi * 16 + lo;
        av[mi] = *(const short8*)((const char*)Al[cur] + r * 128 + ((kk * 64 + hi * 16) ^ ((r & 7) << 4)));
      }
      #pragma unroll
      for (int ni = 0; ni < 4; ++ni) {
        int r = wc * 64 + ni * 16 + lo;
        bv_[ni] = *(const short8*)((const char*)Bl[cur] + r * 128 + ((kk * 64 + hi * 16) ^ ((r & 7) << 4)));
      }
      #pragma unroll
      for (int mi = 0; mi < 4; ++mi)
        #pragma unroll
        for (int ni = 0; ni < 4; ++ni)
          acc[mi][ni] = __builtin_amdgcn_mfma_f32_16x16x32_bf16(av[mi], bv_[ni], acc[mi][ni], 0, 0, 0);
    }
    if (kt + 1 < KT) {
      asm volatile("s_waitcnt vmcnt(0)" ::: "memory");
      __builtin_amdgcn_s_barrier();
      cur ^= 1;
    }
  }
  int mbase = bm * 128 + wr * 64;
  int nbase = bn * 128 + wc * 64;
  #pragma unroll
  for (int mi = 0; mi < 4; ++mi)
    #pragma unroll
    for (int ni = 0; ni < 4; ++ni)
      #pragma unroll
      for (int r = 0; r < 4; ++r) {
        int gm = mbase + mi * 16 + hi * 4 + r;
        int gn = nbase + ni * 16 + lo;
        float v = acc[mi][ni][r] + (g.rowbias ? g.bias[gm] : g.bias[gn]);
        if (GELU) v = 0.5f * v * (1.0f + erff(v * 0.70710678118654752f));
        if (OUTBF) ((unsigned short*)g.C)[(size_t)gm * g.N + gn] = f2bf(v);
        else       ((float*)g.C)[(size_t)gm * g.N + gn] = v;
      }
}

// ---------------- device body: split-K NT GEMM 64x64, dbuf 2-phase (LDS passed in) ----------------
template <int GELU, int OUTBF, int PARTIAL>
__device__ __forceinline__ void gemm64_body(char* shm, GB g, int K, int kLen,
                                            int bm, int bn, int bz) {
  char* Al = shm;            // 2 x 8 KB
  char* Bl = shm + 16384;    // 2 x 8 KB
  int t = threadIdx.x, w = t >> 6, lane = t & 63;
  int hi = lane >> 4, lo = lane & 15;
  int wr = w >> 1, wc = w & 1;
  f32x4 acc[2][2] = {};
  size_t rb = (size_t)K * 2;
  const char* Abase = (const char*)g.A + (size_t)(bm * 64) * rb + (size_t)bz * kLen * 2;
  const char* Bbase = (const char*)g.Bt + (size_t)(bn * 64) * rb + (size_t)bz * kLen * 2;
  int KT = kLen >> 6;
  auto STAGE = [&](int buf, int kt) {
    int k0b = kt * 128;
    #pragma unroll
    for (int c = 0; c < 2; ++c) {
      int base = (c * 4 + w) << 10;
      int o = base + lane * 16;
      int row = o >> 7, cb = o & 127;
      int scb = cb ^ ((row & 7) << 4);
      gload_lds16(Abase + (size_t)row * rb + (k0b + scb), Al + buf * 8192 + base);
      gload_lds16(Bbase + (size_t)row * rb + (k0b + scb), Bl + buf * 8192 + base);
    }
  };
  STAGE(0, 0);
  asm volatile("s_waitcnt vmcnt(0)" ::: "memory");
  __builtin_amdgcn_s_barrier();
  int cur = 0;
  for (int kt = 0; kt < KT; ++kt) {
    if (kt + 1 < KT) STAGE(cur ^ 1, kt + 1);
    #pragma unroll
    for (int kk = 0; kk < 2; ++kk) {
      short8 av[2], bv_[2];
      #pragma unroll
      for (int mi = 0; mi < 2; ++mi) {
        int r = wr * 32 + mi * 16 + lo;
        av[mi] = *(const short8*)(Al + cur * 8192 + r * 128 + ((kk * 64 + hi * 16) ^ ((r & 7) << 4)));
      }
      #pragma unroll
      for (int ni = 0; ni < 2; ++ni) {
        int r = wc * 32 + ni * 16 + lo;
        bv_[ni] = *(const short8*)(Bl + cur * 8192 + r * 128 + ((kk * 64 + hi * 16) ^ ((r & 7) << 4)));
      }
      #pragma unroll
      for (int mi = 0; mi < 2; ++mi)
        #pragma unroll
        for (int ni = 0; ni < 2; ++ni)
          acc[mi][ni] = __builtin_amdgcn_mfma_f32_16x16x32_bf16(av[mi], bv_[ni], acc[mi][ni], 0, 0, 0);
    }
    if (kt + 1 < KT) {
      asm volatile("s_waitcnt vmcnt(0)" ::: "memory");
      __builtin_amdgcn_s_barrier();
      cur ^= 1;
    }
  }
  int mbase = bm * 64 + wr * 32;
  int nbase = bn * 64 + wc * 32;
  #pragma unroll
  for (int mi = 0; mi < 2; ++mi)
    #pragma unroll
    for (int ni = 0; ni < 2; ++ni)
      #pragma unroll
      for (int r = 0; r < 4; ++r) {
        int gm = mbase + mi * 16 + hi * 4 + r;
        int gn = nbase + ni * 16 + lo;
        if (PARTIAL) {
          ((float*)g.C)[((size_t)bz * g.M + gm) * g.N + gn] = acc[mi][ni][r];
        } else {
          float v = acc[mi][ni][r] + g.bias[gn];
          if (GELU) v = 0.5f * v * (1.0f + erff(v * 0.70710678118654752f));
          if (OUTBF) ((unsigned short*)g.C)[(size_t)gm * g.N + gn] = f2bf(v);
          else       ((float*)g.C)[(size_t)gm * g.N + gn] = v;
        }
      }
}

// ---------------- device body: residual + partials + bias + LayerNorm for one row ----------------
template <int FINAL, int NP>
__device__ __forceinline__ void ln_body(int r, const float* x, const float* y, const float* gb,
                                        const float* g, const float* bb,
                                        float* qf, unsigned short* qb,
                                        const int* zi, const float* zc, float* out,
                                        float* r1, float* r2) {
  const int MN = BB * II * DD;
  int t = threadIdx.x;
  size_t o = (size_t)r * DD;
  float v0 = x[o + t] + gb[t];
  float v1 = x[o + t + 256] + gb[t + 256];
  float v2 = x[o + t + 512] + gb[t + 512];
  #pragma unroll
  for (int p = 0; p < NP; ++p) {
    size_t po = (size_t)p * MN + o;
    v0 += y[po + t];
    v1 += y[po + t + 256];
    v2 += y[po + t + 512];
  }
  float s = v0 + v1 + v2, ss = v0 * v0 + v1 * v1 + v2 * v2;
  #pragma unroll
  for (int o2 = 32; o2; o2 >>= 1) { s += __shfl_xor(s, o2); ss += __shfl_xor(ss, o2); }
  if ((t & 63) == 0) { r1[t >> 6] = s; r2[t >> 6] = ss; }
  __syncthreads();
  s = r1[0] + r1[1] + r1[2] + r1[3];
  ss = r2[0] + r2[1] + r2[2] + r2[3];
  float mean = s * (1.0f / DD);
  float var = ss * (1.0f / DD) - mean * mean;
  float inv = rsqrtf(var + 1e-12f);
  float w0 = (v0 - mean) * inv * g[t] + bb[t];
  float w1 = (v1 - mean) * inv * g[t + 256] + bb[t + 256];
  float w2 = (v2 - mean) * inv * g[t + 512] + bb[t + 512];
  if (FINAL) {
    int z = zi[r];
    out[o + t] = z ? zc[t] : w0;
    out[o + t + 256] = z ? zc[t + 256] : w1;
    out[o + t + 512] = z ? zc[t + 512] : w2;
  } else {
    qf[o + t] = w0; qf[o + t + 256] = w1; qf[o + t + 512] = w2;
    qb[o + t] = f2bf(w0); qb[o + t + 256] = f2bf(w1); qb[o + t + 512] = f2bf(w2);
  }
  __syncthreads();
}

// ---------------- mega: Wo -> LN1 -> FFN1 -> FFN2 -> LN2 (grid-barrier fused) ----------------
struct MegaArgs {
  unsigned* cnt;
  const unsigned short* ctx; const unsigned short* WoT; const float* bo;
  float* att_o; float* qf; unsigned short* qb;
  const float* ln1g; const float* ln1b;
  const unsigned short* W1T; const float* b1; unsigned short* ffh;
  const unsigned short* W2T; const float* b2; float* ffo;
  const float* ln2g; const float* ln2b;
  int fin; const int* zi; const float* zc; float* out;
};

__global__ __launch_bounds__(256) void mega_kernel(MegaArgs a) {
  __shared__ char shm[32768];
  __shared__ float r1[4], r2[4];
  int bid = blockIdx.x;
  // P0: Wo projection, split-K=2 -> att_o partials (96 workers)
  if (bid < 96) {
    GB gO = { a.ctx, a.WoT, nullptr, a.att_o, BB * II, DD, 0 };
    gemm64_body<0, 0, 1>(shm, gO, DD, DD / 2, bid & 3, (bid >> 2) % 12, bid / 48);
  }
  gbar(a.cnt + 0, MEGA_NB);
  // P1: LN1 (residual qf + 2 partials + bo)
  for (int r = bid; r < BB * II; r += MEGA_NB)
    ln_body<0, 2>(r, a.qf, a.att_o, a.bo, a.ln1g, a.ln1b, a.qf, a.qb, nullptr, nullptr, nullptr, r1, r2);
  gbar(a.cnt + 1, MEGA_NB);
  // P2: FFN1 (GELU, bf16 out), 192 tiles
  {
    GB gF1 = { a.qb, a.W1T, a.b1, a.ffh, BB * II, FF, 0 };
    gemm64_body<1, 1, 0>(shm, gF1, DD, DD, bid & 3, bid >> 2, 0);
  }
  gbar(a.cnt + 2, MEGA_NB);
  // P3: FFN2 split-K=4 -> ffo partials, 192 workers
  {
    GB gF2 = { a.ffh, a.W2T, nullptr, a.ffo, BB * II, DD, 0 };
    gemm64_body<0, 0, 1>(shm, gF2, FF, FF / 4, bid & 3, (bid >> 2) % 12, bid / 48);
  }
  gbar(a.cnt + 3, MEGA_NB);
  // P4: LN2 (residual + 4 partials + b2); final layer fuses zero-context -> out
  if (a.fin) {
    for (int r = bid; r < BB * II; r += MEGA_NB)
      ln_body<1, 4>(r, a.qf, a.ffo, a.b2, a.ln2g, a.ln2b, nullptr, nullptr, a.zi, a.zc, a.out, r1, r2);
  } else {
    for (int r = bid; r < BB * II; r += MEGA_NB)
      ln_body<0, 4>(r, a.qf, a.ffo, a.b2, a.ln2g, a.ln2b, a.qf, a.qb, nullptr, nullptr, nullptr, r1, r2);
  }
}

// ---------------- fused attention per (b,h): Qproj + QK^T + softmax + PV ----------------
#define ATTN_LDS 145664
__global__ __launch_bounds__(256) void attn_kernel(
    const unsigned short* __restrict__ qbuf, const unsigned short* __restrict__ WqTl,
    const float* __restrict__ bql, const unsigned short* __restrict__ khb,
    const unsigned short* __restrict__ vTall, const unsigned long long* __restrict__ pmask,
    unsigned short* __restrict__ ctx) {
  extern __shared__ char lds[];
  char* Qd = lds;
  char* KP = lds + 8192;
  char* Vd = lds + 8192 + 65536;
  unsigned long long* pm = (unsigned long long*)(lds + 139264);
  float* red  = (float*)(lds + 143360);
  float* red2 = (float*)(lds + 144384);
  float* rnv  = (float*)(lds + 145408);
  int bh = blockIdx.x;
  int b = bh / HH, h = bh - b * HH;
  int t = threadIdx.x, w = t >> 6, l = t & 63, hi = l >> 4, lo = l & 15;
  int o16 = l * 16, ro = o16 >> 7, cb = o16 & 127;

  const char* vsrc = (const char*)vTall + (size_t)(h * 64) * 4096 + (size_t)b * 1024;
  #pragma unroll
  for (int rr = 0; rr < 16; ++rr) {
    int rv = w * 16 + rr;
    gload_lds16(vsrc + (size_t)rv * 4096 + ((l * 16) ^ ((rv & 7) << 4)), Vd + rv * 1024);
  }
  if (w == 0) {
    const char* psrc = (const char*)pmask + (size_t)b * 4096;
    #pragma unroll
    for (int c = 0; c < 4; ++c) gload_lds16(psrc + c * 1024 + l * 16, (char*)pm + c * 1024);
  }

  const char* Aq = (const char*)qbuf + (size_t)(b * II) * 1536;
  const char* Bq = (const char*)WqTl + (size_t)(h * 64) * 1536;
  f32x4 qacc[4] = {};
  #pragma unroll
  for (int cc = 0; cc < 2; ++cc) {
    int ch = w * 2 + cc, row = ch * 8 + ro;
    int scb = cb ^ ((row & 7) << 4);
    gload_lds16(Aq + (size_t)row * 1536 + scb, KP + ch * 1024);
    gload_lds16(Bq + (size_t)row * 1536 + scb, KP + 8192 + ch * 1024);
  }
  __syncthreads();
  for (int kt = 0; kt < 12; ++kt) {
    int cur = (kt & 1) * 16384;
    if (kt < 11) {
      int nxt = ((kt + 1) & 1) * 16384;
      int kb = (kt + 1) * 128;
      #pragma unroll
      for (int cc = 0; cc < 2; ++cc) {
        int ch = w * 2 + cc, row = ch * 8 + ro;
        int scb = kb + (cb ^ ((row & 7) << 4));
        gload_lds16(Aq + (size_t)row * 1536 + scb, KP + nxt + ch * 1024);
        gload_lds16(Bq + (size_t)row * 1536 + scb, KP + nxt + 8192 + ch * 1024);
      }
    }
    #pragma unroll
    for (int kk = 0; kk < 2; ++kk) {
      int ra = w * 16 + lo;
      short8 av = *(const short8*)(KP + cur + ra * 128 + ((kk * 64 + hi * 16) ^ ((ra & 7) << 4)));
      #pragma unroll
      for (int ni = 0; ni < 4; ++ni) {
        int rb2 = ni * 16 + lo;
        short8 bv = *(const short8*)(KP + cur + 8192 + rb2 * 128 + ((kk * 64 + hi * 16) ^ ((rb2 & 7) << 4)));
        qacc[ni] = __builtin_amdgcn_mfma_f32_16x16x32_bf16(av, bv, qacc[ni], 0, 0, 0);
      }
    }
    __syncthreads();
  }
  #pragma unroll
  for (int ni = 0; ni < 4; ++ni)
    #pragma unroll
    for (int r = 0; r < 4; ++r) {
      int row = w * 16 + hi * 4 + r, col = ni * 16 + lo;
      float v = qacc[ni][r] + bql[h * 64 + col];
      *(unsigned short*)(Qd + row * 128 + ((col * 2) ^ ((row & 7) << 4))) = f2bf(v);
    }
  const char* Ks = (const char*)khb + (size_t)(b * SS) * 1536 + h * 128;
  #pragma unroll
  for (int cc = 0; cc < 16; ++cc) {
    int ch = w * 16 + cc, row = ch * 8 + ro;
    int scb = cb ^ ((row & 7) << 4);
    gload_lds16(Ks + (size_t)row * 1536 + scb, KP + ch * 1024);
  }
  __syncthreads();

  f32x4 acc[4][8] = {};
  #pragma unroll
  for (int kk = 0; kk < 2; ++kk) {
    short8 av[4];
    #pragma unroll
    for (int mi = 0; mi < 4; ++mi) {
      int ra = mi * 16 + lo;
      av[mi] = *(const short8*)(Qd + ra * 128 + ((kk * 64 + hi * 16) ^ ((ra & 7) << 4)));
    }
    #pragma unroll
    for (int ni = 0; ni < 8; ++ni) {
      int rk = w * 128 + ni * 16 + lo;
      short8 bv = *(const short8*)(KP + rk * 128 + ((kk * 64 + hi * 16) ^ ((rk & 7) << 4)));
      #pragma unroll
      for (int mi = 0; mi < 4; ++mi)
        acc[mi][ni] = __builtin_amdgcn_mfma_f32_16x16x32_bf16(av[mi], bv, acc[mi][ni], 0, 0, 0);
    }
  }
  #pragma unroll
  for (int mi = 0; mi < 4; ++mi)
    #pragma unroll
    for (int r = 0; r < 4; ++r) {
      float m = acc[mi][0][r];
      #pragma unroll
      for (int ni = 1; ni < 8; ++ni) m = fmaxf(m, acc[mi][ni][r]);
      #pragma unroll
      for (int xm = 1; xm <= 8; xm <<= 1) m = fmaxf(m, __shfl_xor(m, xm));
      if (lo == 0) red[(mi * 16 + hi * 4 + r) * 4 + w] = m;
    }
  __syncthreads();
  #pragma unroll
  for (int mi = 0; mi < 4; ++mi)
    #pragma unroll
    for (int r = 0; r < 4; ++r) {
      int row = mi * 16 + hi * 4 + r;
      float4 rm4 = *(const float4*)&red[row * 4];
      float gm = fmaxf(fmaxf(rm4.x, rm4.y), fmaxf(rm4.z, rm4.w));
      unsigned long long w0 = pm[row * 8 + w * 2 + 0];
      unsigned long long w1 = pm[row * 8 + w * 2 + 1];
      float s = 0.f;
      #pragma unroll
      for (int ni = 0; ni < 8; ++ni) {
        int sl = ni * 16 + lo;
        unsigned long long word = (sl < 64) ? w0 : w1;
        float in = ((word >> (sl & 63)) & 1ull) ? 1.0f : 0.0f;
        float e = __expf((acc[mi][ni][r] - gm) * 0.125f) * in;
        s += e;
        int sbyte = w * 256 + ni * 32 + lo * 2;
        *(unsigned short*)(KP + row * 1024 + (sbyte ^ ((row & 7) << 4))) = f2bf(e);
      }
      #pragma unroll
      for (int xm = 1; xm <= 8; xm <<= 1) s += __shfl_xor(s, xm);
      if (lo == 0) red2[row * 4 + w] = s;
    }
  __syncthreads();
  if (w == 0 && lo == 0) {
    #pragma unroll
    for (int mi = 0; mi < 4; ++mi)
      #pragma unroll
      for (int r = 0; r < 4; ++r) {
        int row = mi * 16 + hi * 4 + r;
        float4 s4 = *(const float4*)&red2[row * 4];
        rnv[row] = 1.0f / ((s4.x + s4.y) + (s4.z + s4.w));
      }
  }
  __syncthreads();
  f32x4 pacc[4] = {};
  for (int kk = 0; kk < 16; ++kk) {
    int rv = w * 16 + lo;
    short8 bv = *(const short8*)(Vd + rv * 1024 + ((kk * 64 + hi * 16) ^ ((rv & 7) << 4)));
    #pragma unroll
    for (int mi = 0; mi < 4; ++mi) {
      int ra = mi * 16 + lo;
      short8 av = *(const short8*)(KP + ra * 1024 + ((kk * 64 + hi * 16) ^ ((ra & 7) << 4)));
      pacc[mi] = __builtin_amdgcn_mfma_f32_16x16x32_bf16(av, bv, pacc[mi], 0, 0, 0);
    }
  }
  #pragma unroll
  for (int mi = 0; mi < 4; ++mi)
    #pragma unroll
    for (int r = 0; r < 4; ++r) {
      int row = mi * 16 + hi * 4 + r;
      ctx[(size_t)(b * II + row) * DD + h * 64 + w * 16 + lo] = f2bf(pacc[mi][r] * rnv[row]);
    }
}

extern "C" void kernel_launch(void* const* d_in, const int* in_sizes, int n_in,
                              void* d_out, int out_size, void* d_ws, size_t ws_size,
                              hipStream_t stream) {
  (void)in_sizes; (void)n_in; (void)out_size; (void)ws_size;
  const float* hs0 = (const float*)d_in[0];
  const float* hs1 = (const float*)d_in[1];
  const float* Wq  = (const float*)d_in[3];
  const float* bq  = (const float*)d_in[4];
  const float* Wk  = (const float*)d_in[5];
  const float* bk  = (const float*)d_in[6];
  const float* Wv  = (const float*)d_in[7];
  const float* bv  = (const float*)d_in[8];
  const float* Wo  = (const float*)d_in[9];
  const float* bo  = (const float*)d_in[10];
  const float* ln1g = (const float*)d_in[11];
  const float* ln1b = (const float*)d_in[12];
  const float* W1  = (const float*)d_in[13];
  const float* b1  = (const float*)d_in[14];
  const float* W2  = (const float*)d_in[15];
  const float* b2  = (const float*)d_in[16];
  const float* ln2g = (const float*)d_in[17];
  const float* ln2b = (const float*)d_in[18];
  const float* zc  = (const float*)d_in[19];
  const int*   mask = (const int*)d_in[20];

  char* ws = (char*)d_ws;
  size_t off = 0;
  auto alloc = [&](size_t bytes) { size_t o = off; off += (bytes + 255) & ~(size_t)255; return o; };

  unsigned short* WT4 = (unsigned short*)(ws + alloc((size_t)4 * LL * DD * DD * 2));
  unsigned short* W1T = (unsigned short*)(ws + alloc((size_t)LL * FF * DD * 2));
  unsigned short* W2T = (unsigned short*)(ws + alloc((size_t)LL * DD * FF * 2));
  unsigned short* hsb = (unsigned short*)(ws + alloc((size_t)2 * BB * SS * DD * 2));
  float*          qf  = (float*)(ws + alloc((size_t)BB * II * DD * 4));
  unsigned short* qb  = (unsigned short*)(ws + alloc((size_t)BB * II * DD * 2));
  unsigned short* khb = (unsigned short*)(ws + alloc((size_t)LL * BB * SS * DD * 2));
  unsigned short* vTall = (unsigned short*)(ws + alloc((size_t)LL * DD * BB * SS * 2));
  unsigned short* ctxb = (unsigned short*)(ws + alloc((size_t)BB * II * DD * 2));
  float*          att_o = (float*)(ws + alloc((size_t)2 * BB * II * DD * 4));
  unsigned short* ffh = (unsigned short*)(ws + alloc((size_t)BB * II * FF * 2));
  float*          ffo = (float*)(ws + alloc((size_t)4 * BB * II * DD * 4));
  unsigned long long* pmask = (unsigned long long*)(ws + alloc((size_t)BB * II * 8 * 8));
  unsigned char*  emask = (unsigned char*)(ws + alloc((size_t)BB * II * SS));
  int*            zib = (int*)(ws + alloc((size_t)BB * II * 4));
  unsigned*       cnts = (unsigned*)(ws + alloc(8 * sizeof(unsigned)));

  unsigned short* WqT = WT4 + 0 * (size_t)LL * DD * DD;
  unsigned short* WkT = WT4 + 1 * (size_t)LL * DD * DD;
  unsigned short* WvT = WT4 + 2 * (size_t)LL * DD * DD;
  unsigned short* WoT = WT4 + 3 * (size_t)LL * DD * DD;

  (void)hipFuncSetAttribute((const void*)attn_kernel,
                            hipFuncAttributeMaxDynamicSharedMemorySize, ATTN_LDS);

  // zero the grid-barrier counters (deterministic per call; capturable)
  hipMemsetAsync(cnts, 0, 8 * sizeof(unsigned), stream);

  TC tc = { { Wq, Wk, Wv, Wo, W1, W2 } };
  prep1_kernel<<<3520, 256, 0, stream>>>(tc, WT4, W1T, W2T, hs0, hs1,
                                         hsb, hsb + (size_t)BB * SS * DD,
                                         mask, zib, pmask, emask);
  pool3_kernel<<<dim3(BB * II, 3), 256, 0, stream>>>(hs0, emask, qf, qb);

  {
    const unsigned short* h0 = hsb;
    const unsigned short* h1 = hsb + (size_t)BB * SS * DD;
    GB gK0 = { h0, WkT, bk, khb, BB * SS, DD, 0 };
    GB gV0 = { WvT, h0, bv, vTall, DD, BB * SS, 1 };
    GB gK1 = { h1, WkT + (size_t)DD * DD, bk + DD, khb + (size_t)BB * SS * DD, BB * SS, DD, 0 };
    GB gV1 = { WvT + (size_t)DD * DD, h1, bv + DD, vTall + (size_t)DD * BB * SS, DD, BB * SS, 1 };
    gemm_nt<0, 1><<<dim3(16, 6, 4), 256, 0, stream>>>(gK0, gV0, gK1, gV1, DD);
  }

  for (int l = 0; l < LL; ++l) {
    const unsigned short* khl = khb + (size_t)l * BB * SS * DD;
    const unsigned short* vTl = vTall + (size_t)l * DD * BB * SS;
    attn_kernel<<<dim3(BB * HH), 256, ATTN_LDS, stream>>>(
        qb, WqT + (size_t)l * DD * DD, bq + l * DD, khl, vTl, pmask, ctxb);
    MegaArgs ma;
    ma.cnt = cnts + l * 4;
    ma.ctx = ctxb; ma.WoT = WoT + (size_t)l * DD * DD; ma.bo = bo + l * DD;
    ma.att_o = att_o; ma.qf = qf; ma.qb = qb;
    ma.ln1g = ln1g + l * DD; ma.ln1b = ln1b + l * DD;
    ma.W1T = W1T + (size_t)l * FF * DD; ma.b1 = b1 + l * FF; ma.ffh = ffh;
    ma.W2T = W2T + (size_t)l * DD * FF; ma.b2 = b2 + l * DD; ma.ffo = ffo;
    ma.ln2g = ln2g + l * DD; ma.ln2b = ln2b + l * DD;
    ma.fin = (l == LL - 1); ma.zi = zib; ma.zc = zc; ma.out = (float*)d_out;
    mega_kernel<<<MEGA_NB, 256, 0, stream>>>(ma);
  }
}

// Round 14
// 200.460 us; speedup vs baseline: 1.4521x; 1.4521x over previous
//
#include <hip/hip_runtime.h>
#include <hip/hip_bf16.h>
#include <math.h>

#define BB 4
#define SS 512
#define DD 768
#define II 64
#define LL 2
#define HH 12
#define FF 3072

using short8 = __attribute__((ext_vector_type(8))) short;
using f32x4  = __attribute__((ext_vector_type(4))) float;

__device__ __forceinline__ unsigned short f2bf(float x) {
  return __builtin_bit_cast(unsigned short, __float2bfloat16(x));
}

__device__ __forceinline__ void gload_lds16(const void* g, void* l) {
  __builtin_amdgcn_global_load_lds((const __attribute__((address_space(1))) unsigned int*)g,
                                   (__attribute__((address_space(3))) unsigned int*)l, 16, 0, 0);
}

// ---------------- cast hs0/hs1 to bf16 ----------------
__global__ __launch_bounds__(256) void cast2_kernel(const float* __restrict__ a, const float* __restrict__ b,
                                                    unsigned short* __restrict__ oa, unsigned short* __restrict__ ob) {
  int idx = blockIdx.x * 256 + threadIdx.x;
  float4 va = ((const float4*)a)[idx];
  float4 vb = ((const float4*)b)[idx];
  union { unsigned short u[4]; uint2 v; } pa, pb;
  pa.u[0] = f2bf(va.x); pa.u[1] = f2bf(va.y); pa.u[2] = f2bf(va.z); pa.u[3] = f2bf(va.w);
  pb.u[0] = f2bf(vb.x); pb.u[1] = f2bf(vb.y); pb.u[2] = f2bf(vb.z); pb.u[3] = f2bf(vb.w);
  ((uint2*)oa)[idx] = pa.v;
  ((uint2*)ob)[idx] = pb.v;
}

// ---------------- unified transpose+cast for all weights ----------------
struct TC { const float* s[6]; };

__global__ __launch_bounds__(256) void tcast_all(TC src, unsigned short* __restrict__ WT4,
                                                 unsigned short* __restrict__ W1T,
                                                 unsigned short* __restrict__ W2T) {
  __shared__ float tile[32][33];
  int z = blockIdx.z;
  const float* Ws; unsigned short* WTs; int K, N, n0, k0;
  if (z < 8) {
    if (blockIdx.x >= 24) return;
    int widx = z >> 1, l = z & 1;
    Ws = src.s[widx] + (size_t)l * DD * DD;
    WTs = WT4 + ((size_t)widx * 2 + l) * DD * DD;
    K = DD; N = DD; n0 = blockIdx.x * 32; k0 = blockIdx.y * 32;
  } else if (z < 10) {
    int l = z - 8;
    Ws = src.s[4] + (size_t)l * DD * FF;
    WTs = W1T + (size_t)l * FF * DD;
    K = DD; N = FF; n0 = blockIdx.x * 32; k0 = blockIdx.y * 32;
  } else {
    int l = z - 10;
    Ws = src.s[5] + (size_t)l * FF * DD;
    WTs = W2T + (size_t)l * DD * FF;
    K = FF; N = DD; n0 = blockIdx.y * 32; k0 = blockIdx.x * 32;
  }
  int tx = threadIdx.x, ty = threadIdx.y;  // (32,8)
  #pragma unroll
  for (int r = 0; r < 4; ++r) tile[ty + 8 * r][tx] = Ws[(size_t)(k0 + ty + 8 * r) * N + (n0 + tx)];
  __syncthreads();
  #pragma unroll
  for (int r = 0; r < 4; ++r) WTs[(size_t)(n0 + ty + 8 * r) * K + (k0 + tx)] = f2bf(tile[tx][ty + 8 * r]);
}

// ---------------- masked max pooling + zero_indic + bit-packed inclusion mask ----------------
__global__ __launch_bounds__(256) void pool_kernel(const float* __restrict__ hs0, const int* __restrict__ mask,
                                                   int* __restrict__ zi, float* __restrict__ qf,
                                                   unsigned short* __restrict__ qb,
                                                   unsigned long long* __restrict__ pmask) {
  __shared__ float eadd[SS];
  int bi = blockIdx.x;  // b*II + i
  int b = bi >> 6, dz = blockIdx.y, t = threadIdx.x, w = t >> 6;
  const int* mrow = mask + (size_t)bi * SS;
  int m0v = mrow[t], m1v = mrow[t + 256];
  eadd[t] = m0v ? -__builtin_inff() : 0.0f;
  eadd[t + 256] = m1v ? -__builtin_inff() : 0.0f;
  int incl = (m0v == 0) | (m1v == 0);
  int any = __syncthreads_or(incl);
  int z = !any;
  if (dz == 0) {
    unsigned long long w0 = __ballot(z || (m0v == 0));
    unsigned long long w1 = __ballot(z || (m1v == 0));
    if ((t & 63) == 0) {
      pmask[bi * 8 + w] = w0;
      pmask[bi * 8 + 4 + w] = w1;
      if (t == 0) zi[bi] = z;
    }
  }
  const float* hb = hs0 + (size_t)b * SS * DD + dz * 256 + t;
  float m[8];
  #pragma unroll
  for (int j = 0; j < 8; ++j) m[j] = -3.4e38f;
  for (int s0 = 0; s0 < SS; s0 += 8) {
    #pragma unroll
    for (int j = 0; j < 8; ++j)
      m[j] = fmaxf(m[j], hb[(size_t)(s0 + j) * DD] + eadd[s0 + j]);
  }
  float mm = fmaxf(fmaxf(fmaxf(m[0], m[1]), fmaxf(m[2], m[3])),
                   fmaxf(fmaxf(m[4], m[5]), fmaxf(m[6], m[7])));
  size_t o = (size_t)bi * DD + dz * 256 + t;
  qf[o] = mm;
  qb[o] = f2bf(mm);
}

// ---------------- NT GEMM 128x128 (4 problems via z; odd z = transposed block map) ----------------
struct GB { const unsigned short* A; const unsigned short* Bt; const float* bias; void* C;
            int M; int N; int rowbias; };

template <int GELU, int OUTBF>
__global__ __launch_bounds__(256) void gemm_nt(GB g0, GB g1, GB g2, GB g3, int K) {
  __shared__ unsigned short Al[128 * 64];
  __shared__ unsigned short Bl[128 * 64];
  GB g = (blockIdx.z == 0) ? g0 : (blockIdx.z == 1) ? g1 : (blockIdx.z == 2) ? g2 : g3;
  int bm = blockIdx.x, bn = blockIdx.y;
  if (blockIdx.z & 1) { bm = blockIdx.y; bn = blockIdx.x; }
  if (bm * 128 >= g.M) return;
  int t = threadIdx.x, w = t >> 6, lane = t & 63;
  int hi = lane >> 4, lo = lane & 15;
  int wr = w >> 1, wc = w & 1;
  f32x4 acc[4][4] = {};
  const char* Abase = (const char*)g.A + (size_t)(bm * 128) * (size_t)K * 2;
  const char* Bbase = (const char*)g.Bt + (size_t)(bn * 128) * (size_t)K * 2;
  int rowbytes = K * 2;
  int KT = K >> 6;
  for (int kt = 0; kt < KT; ++kt) {
    int k0b = kt * 128;
    #pragma unroll
    for (int c = 0; c < 4; ++c) {
      int base = (c * 4 + w) << 10;
      int o = base + lane * 16;
      int row = o >> 7, cb = o & 127;
      int scb = cb ^ ((row & 7) << 4);
      gload_lds16(Abase + (size_t)row * rowbytes + (k0b + scb), (char*)Al + base);
      gload_lds16(Bbase + (size_t)row * rowbytes + (k0b + scb), (char*)Bl + base);
    }
    __syncthreads();
    #pragma unroll
    for (int kk = 0; kk < 2; ++kk) {
      short8 av[4], bv_[4];
      #pragma unroll
      for (int mi = 0; mi < 4; ++mi) {
        int r = wr * 64 + mi * 16 + lo;
        av[mi] = *(const short8*)((const char*)Al + r * 128 + ((kk * 64 + hi * 16) ^ ((r & 7) << 4)));
      }
      #pragma unroll
      for (int ni = 0; ni < 4; ++ni) {
        int r = wc * 64 + ni * 16 + lo;
        bv_[ni] = *(const short8*)((const char*)Bl + r * 128 + ((kk * 64 + hi * 16) ^ ((r & 7) << 4)));
      }
      #pragma unroll
      for (int mi = 0; mi < 4; ++mi)
        #pragma unroll
        for (int ni = 0; ni < 4; ++ni)
          acc[mi][ni] = __builtin_amdgcn_mfma_f32_16x16x32_bf16(av[mi], bv_[ni], acc[mi][ni], 0, 0, 0);
    }
    __syncthreads();
  }
  int mbase = bm * 128 + wr * 64;
  int nbase = bn * 128 + wc * 64;
  #pragma unroll
  for (int mi = 0; mi < 4; ++mi)
    #pragma unroll
    for (int ni = 0; ni < 4; ++ni)
      #pragma unroll
      for (int r = 0; r < 4; ++r) {
        int gm = mbase + mi * 16 + hi * 4 + r;
        int gn = nbase + ni * 16 + lo;
        float v = acc[mi][ni][r] + (g.rowbias ? g.bias[gm] : g.bias[gn]);
        if (GELU) v = 0.5f * v * (1.0f + erff(v * 0.70710678118654752f));
        if (OUTBF) ((unsigned short*)g.C)[(size_t)gm * g.N + gn] = f2bf(v);
        else       ((float*)g.C)[(size_t)gm * g.N + gn] = v;
      }
}

// ---------------- split-K NT GEMM 64x64, double-buffered 2-phase pipeline ----------------
template <int GELU, int OUTBF, int PARTIAL>
__global__ __launch_bounds__(256) void gemm_sk(GB g, int K, int kLen) {
  __shared__ unsigned short Al[2][64 * 64];
  __shared__ unsigned short Bl[2][64 * 64];
  int bm = blockIdx.x, bn = blockIdx.y, bz = blockIdx.z;
  int t = threadIdx.x, w = t >> 6, lane = t & 63;
  int hi = lane >> 4, lo = lane & 15;
  int wr = w >> 1, wc = w & 1;
  f32x4 acc[2][2] = {};
  size_t rb = (size_t)K * 2;
  const char* Abase = (const char*)g.A + (size_t)(bm * 64) * rb + (size_t)bz * kLen * 2;
  const char* Bbase = (const char*)g.Bt + (size_t)(bn * 64) * rb + (size_t)bz * kLen * 2;
  int KT = kLen >> 6;
  auto STAGE = [&](int buf, int kt) {
    int k0b = kt * 128;
    #pragma unroll
    for (int c = 0; c < 2; ++c) {
      int base = (c * 4 + w) << 10;
      int o = base + lane * 16;
      int row = o >> 7, cb = o & 127;
      int scb = cb ^ ((row & 7) << 4);
      gload_lds16(Abase + (size_t)row * rb + (k0b + scb), (char*)Al[buf] + base);
      gload_lds16(Bbase + (size_t)row * rb + (k0b + scb), (char*)Bl[buf] + base);
    }
  };
  STAGE(0, 0);
  asm volatile("s_waitcnt vmcnt(0)" ::: "memory");
  __builtin_amdgcn_s_barrier();
  int cur = 0;
  for (int kt = 0; kt < KT; ++kt) {
    if (kt + 1 < KT) STAGE(cur ^ 1, kt + 1);
    #pragma unroll
    for (int kk = 0; kk < 2; ++kk) {
      short8 av[2], bv_[2];
      #pragma unroll
      for (int mi = 0; mi < 2; ++mi) {
        int r = wr * 32 + mi * 16 + lo;
        av[mi] = *(const short8*)((const char*)Al[cur] + r * 128 + ((kk * 64 + hi * 16) ^ ((r & 7) << 4)));
      }
      #pragma unroll
      for (int ni = 0; ni < 2; ++ni) {
        int r = wc * 32 + ni * 16 + lo;
        bv_[ni] = *(const short8*)((const char*)Bl[cur] + r * 128 + ((kk * 64 + hi * 16) ^ ((r & 7) << 4)));
      }
      #pragma unroll
      for (int mi = 0; mi < 2; ++mi)
        #pragma unroll
        for (int ni = 0; ni < 2; ++ni)
          acc[mi][ni] = __builtin_amdgcn_mfma_f32_16x16x32_bf16(av[mi], bv_[ni], acc[mi][ni], 0, 0, 0);
    }
    if (kt + 1 < KT) {
      asm volatile("s_waitcnt vmcnt(0)" ::: "memory");
      __builtin_amdgcn_s_barrier();
      cur ^= 1;
    }
  }
  int mbase = bm * 64 + wr * 32;
  int nbase = bn * 64 + wc * 32;
  #pragma unroll
  for (int mi = 0; mi < 2; ++mi)
    #pragma unroll
    for (int ni = 0; ni < 2; ++ni)
      #pragma unroll
      for (int r = 0; r < 4; ++r) {
        int gm = mbase + mi * 16 + hi * 4 + r;
        int gn = nbase + ni * 16 + lo;
        if (PARTIAL) {
          ((float*)g.C)[((size_t)bz * g.M + gm) * g.N + gn] = acc[mi][ni][r];
        } else {
          float v = acc[mi][ni][r] + g.bias[gn];
          if (GELU) v = 0.5f * v * (1.0f + erff(v * 0.70710678118654752f));
          if (OUTBF) ((unsigned short*)g.C)[(size_t)gm * g.N + gn] = f2bf(v);
          else       ((float*)g.C)[(size_t)gm * g.N + gn] = v;
        }
      }
}

// ---------------- fused LN1 + FFN1: per block, LN its 64 A-rows into LDS, then GEMM ----------------
// LDS: A 12 chunks x 8KB (swizzled bf16) = 96KB | B dbuf 2x8KB = 16KB  -> 112KB
#define FFN1_LDS (98304 + 16384)
__global__ __launch_bounds__(256) void ffn1_kernel(
    const float* __restrict__ qf_in, const float* __restrict__ att_o, const float* __restrict__ bo,
    const float* __restrict__ g, const float* __restrict__ bb, float* __restrict__ qf_out,
    const unsigned short* __restrict__ W1T, const float* __restrict__ b1,
    unsigned short* __restrict__ ffh) {
  extern __shared__ char shm[];
  char* Adata = shm;           // 96 KB
  char* Bl = shm + 98304;      // 16 KB
  const int MN = BB * II * DD;
  int bm = blockIdx.x, bn = blockIdx.y;
  int t = threadIdx.x, w = t >> 6, lane = t & 63;
  int hi = lane >> 4, lo = lane & 15;
  int wr = w >> 1, wc = w & 1;

  // ---- Phase 1: LN1 for rows bm*64..+63 -> Adata (chunk-swizzled bf16); bn==0 writes qf_out ----
  for (int i = 0; i < 16; ++i) {
    int rloc = w + 4 * i;             // 0..63
    int row = bm * 64 + rloc;
    size_t o = (size_t)row * DD;
    float v[12];
    float s = 0.f, ss = 0.f;
    #pragma unroll
    for (int j = 0; j < 12; ++j) {
      int c = lane + 64 * j;
      float x = qf_in[o + c] + bo[c] + att_o[o + c] + att_o[MN + o + c];
      v[j] = x; s += x; ss += x * x;
    }
    #pragma unroll
    for (int o2 = 32; o2; o2 >>= 1) { s += __shfl_xor(s, o2); ss += __shfl_xor(ss, o2); }
    float mean = s * (1.0f / DD);
    float var = ss * (1.0f / DD) - mean * mean;
    float inv = rsqrtf(var + 1e-12f);
    #pragma unroll
    for (int j = 0; j < 12; ++j) {
      int c = lane + 64 * j;
      float wv = (v[j] - mean) * inv * g[c] + bb[c];
      *(unsigned short*)(Adata + j * 8192 + rloc * 128 + ((lane * 2) ^ ((rloc & 7) << 4))) = f2bf(wv);
      if (bn == 0) qf_out[o + c] = wv;
    }
  }
  __syncthreads();

  // ---- Phase 2: 64x64 GEMM, A from LDS, B dbuf-staged (K=768, 12 chunks) ----
  f32x4 acc[2][2] = {};
  size_t rb = (size_t)DD * 2;
  const char* Bbase = (const char*)W1T + (size_t)(bn * 64) * rb;
  auto STAGEB = [&](int buf, int kt) {
    int k0b = kt * 128;
    #pragma unroll
    for (int c = 0; c < 2; ++c) {
      int base = (c * 4 + w) << 10;
      int o = base + lane * 16;
      int row = o >> 7, cb = o & 127;
      int scb = cb ^ ((row & 7) << 4);
      gload_lds16(Bbase + (size_t)row * rb + (k0b + scb), Bl + buf * 8192 + base);
    }
  };
  STAGEB(0, 0);
  asm volatile("s_waitcnt vmcnt(0)" ::: "memory");
  __builtin_amdgcn_s_barrier();
  int cur = 0;
  for (int kt = 0; kt < 12; ++kt) {
    if (kt + 1 < 12) STAGEB(cur ^ 1, kt + 1);
    const char* Al = Adata + kt * 8192;
    #pragma unroll
    for (int kk = 0; kk < 2; ++kk) {
      short8 av[2], bv_[2];
      #pragma unroll
      for (int mi = 0; mi < 2; ++mi) {
        int r = wr * 32 + mi * 16 + lo;
        av[mi] = *(const short8*)(Al + r * 128 + ((kk * 64 + hi * 16) ^ ((r & 7) << 4)));
      }
      #pragma unroll
      for (int ni = 0; ni < 2; ++ni) {
        int r = wc * 32 + ni * 16 + lo;
        bv_[ni] = *(const short8*)(Bl + cur * 8192 + r * 128 + ((kk * 64 + hi * 16) ^ ((r & 7) << 4)));
      }
      #pragma unroll
      for (int mi = 0; mi < 2; ++mi)
        #pragma unroll
        for (int ni = 0; ni < 2; ++ni)
          acc[mi][ni] = __builtin_amdgcn_mfma_f32_16x16x32_bf16(av[mi], bv_[ni], acc[mi][ni], 0, 0, 0);
    }
    if (kt + 1 < 12) {
      asm volatile("s_waitcnt vmcnt(0)" ::: "memory");
      __builtin_amdgcn_s_barrier();
      cur ^= 1;
    }
  }
  int mbase = bm * 64 + wr * 32;
  int nbase = bn * 64 + wc * 32;
  #pragma unroll
  for (int mi = 0; mi < 2; ++mi)
    #pragma unroll
    for (int ni = 0; ni < 2; ++ni)
      #pragma unroll
      for (int r = 0; r < 4; ++r) {
        int gm = mbase + mi * 16 + hi * 4 + r;
        int gn = nbase + ni * 16 + lo;
        float v = acc[mi][ni][r] + b1[gn];
        v = 0.5f * v * (1.0f + erff(v * 0.70710678118654752f));
        ffh[(size_t)gm * FF + gn] = f2bf(v);
      }
}

// ---------------- fused attention per (b,h): Qproj + QK^T + softmax + PV ----------------
#define ATTN_LDS 145664
__global__ __launch_bounds__(256) void attn_kernel(
    const unsigned short* __restrict__ qbuf, const unsigned short* __restrict__ WqTl,
    const float* __restrict__ bql, const unsigned short* __restrict__ khb,
    const unsigned short* __restrict__ vTall, const unsigned long long* __restrict__ pmask,
    unsigned short* __restrict__ ctx) {
  extern __shared__ char lds[];
  char* Qd = lds;
  char* KP = lds + 8192;
  char* Vd = lds + 8192 + 65536;
  unsigned long long* pm = (unsigned long long*)(lds + 139264);
  float* red  = (float*)(lds + 143360);
  float* red2 = (float*)(lds + 144384);
  float* rnv  = (float*)(lds + 145408);
  int bh = blockIdx.x;
  int b = bh / HH, h = bh - b * HH;
  int t = threadIdx.x, w = t >> 6, l = t & 63, hi = l >> 4, lo = l & 15;
  int o16 = l * 16, ro = o16 >> 7, cb = o16 & 127;

  const char* vsrc = (const char*)vTall + (size_t)(h * 64) * 4096 + (size_t)b * 1024;
  #pragma unroll
  for (int rr = 0; rr < 16; ++rr) {
    int rv = w * 16 + rr;
    gload_lds16(vsrc + (size_t)rv * 4096 + ((l * 16) ^ ((rv & 7) << 4)), Vd + rv * 1024);
  }
  if (w == 0) {
    const char* psrc = (const char*)pmask + (size_t)b * 4096;
    #pragma unroll
    for (int c = 0; c < 4; ++c) gload_lds16(psrc + c * 1024 + l * 16, (char*)pm + c * 1024);
  }

  const char* Aq = (const char*)qbuf + (size_t)(b * II) * 1536;
  const char* Bq = (const char*)WqTl + (size_t)(h * 64) * 1536;
  f32x4 qacc[4] = {};
  #pragma unroll
  for (int cc = 0; cc < 2; ++cc) {
    int ch = w * 2 + cc, row = ch * 8 + ro;
    int scb = cb ^ ((row & 7) << 4);
    gload_lds16(Aq + (size_t)row * 1536 + scb, KP + ch * 1024);
    gload_lds16(Bq + (size_t)row * 1536 + scb, KP + 8192 + ch * 1024);
  }
  __syncthreads();
  for (int kt = 0; kt < 12; ++kt) {
    int cur = (kt & 1) * 16384;
    if (kt < 11) {
      int nxt = ((kt + 1) & 1) * 16384;
      int kb = (kt + 1) * 128;
      #pragma unroll
      for (int cc = 0; cc < 2; ++cc) {
        int ch = w * 2 + cc, row = ch * 8 + ro;
        int scb = kb + (cb ^ ((row & 7) << 4));
        gload_lds16(Aq + (size_t)row * 1536 + scb, KP + nxt + ch * 1024);
        gload_lds16(Bq + (size_t)row * 1536 + scb, KP + nxt + 8192 + ch * 1024);
      }
    }
    #pragma unroll
    for (int kk = 0; kk < 2; ++kk) {
      int ra = w * 16 + lo;
      short8 av = *(const short8*)(KP + cur + ra * 128 + ((kk * 64 + hi * 16) ^ ((ra & 7) << 4)));
      #pragma unroll
      for (int ni = 0; ni < 4; ++ni) {
        int rb2 = ni * 16 + lo;
        short8 bv = *(const short8*)(KP + cur + 8192 + rb2 * 128 + ((kk * 64 + hi * 16) ^ ((rb2 & 7) << 4)));
        qacc[ni] = __builtin_amdgcn_mfma_f32_16x16x32_bf16(av, bv, qacc[ni], 0, 0, 0);
      }
    }
    __syncthreads();
  }
  #pragma unroll
  for (int ni = 0; ni < 4; ++ni)
    #pragma unroll
    for (int r = 0; r < 4; ++r) {
      int row = w * 16 + hi * 4 + r, col = ni * 16 + lo;
      float v = qacc[ni][r] + bql[h * 64 + col];
      *(unsigned short*)(Qd + row * 128 + ((col * 2) ^ ((row & 7) << 4))) = f2bf(v);
    }
  const char* Ks = (const char*)khb + (size_t)(b * SS) * 1536 + h * 128;
  #pragma unroll
  for (int cc = 0; cc < 16; ++cc) {
    int ch = w * 16 + cc, row = ch * 8 + ro;
    int scb = cb ^ ((row & 7) << 4);
    gload_lds16(Ks + (size_t)row * 1536 + scb, KP + ch * 1024);
  }
  __syncthreads();

  f32x4 acc[4][8] = {};
  #pragma unroll
  for (int kk = 0; kk < 2; ++kk) {
    short8 av[4];
    #pragma unroll
    for (int mi = 0; mi < 4; ++mi) {
      int ra = mi * 16 + lo;
      av[mi] = *(const short8*)(Qd + ra * 128 + ((kk * 64 + hi * 16) ^ ((ra & 7) << 4)));
    }
    #pragma unroll
    for (int ni = 0; ni < 8; ++ni) {
      int rk = w * 128 + ni * 16 + lo;
      short8 bv = *(const short8*)(KP + rk * 128 + ((kk * 64 + hi * 16) ^ ((rk & 7) << 4)));
      #pragma unroll
      for (int mi = 0; mi < 4; ++mi)
        acc[mi][ni] = __builtin_amdgcn_mfma_f32_16x16x32_bf16(av[mi], bv, acc[mi][ni], 0, 0, 0);
    }
  }
  #pragma unroll
  for (int mi = 0; mi < 4; ++mi)
    #pragma unroll
    for (int r = 0; r < 4; ++r) {
      float m = acc[mi][0][r];
      #pragma unroll
      for (int ni = 1; ni < 8; ++ni) m = fmaxf(m, acc[mi][ni][r]);
      #pragma unroll
      for (int xm = 1; xm <= 8; xm <<= 1) m = fmaxf(m, __shfl_xor(m, xm));
      if (lo == 0) red[(mi * 16 + hi * 4 + r) * 4 + w] = m;
    }
  __syncthreads();
  #pragma unroll
  for (int mi = 0; mi < 4; ++mi)
    #pragma unroll
    for (int r = 0; r < 4; ++r) {
      int row = mi * 16 + hi * 4 + r;
      float4 rm4 = *(const float4*)&red[row * 4];
      float gm = fmaxf(fmaxf(rm4.x, rm4.y), fmaxf(rm4.z, rm4.w));
      unsigned long long w0 = pm[row * 8 + w * 2 + 0];
      unsigned long long w1 = pm[row * 8 + w * 2 + 1];
      float s = 0.f;
      #pragma unroll
      for (int ni = 0; ni < 8; ++ni) {
        int sl = ni * 16 + lo;
        unsigned long long word = (sl < 64) ? w0 : w1;
        float in = ((word >> (sl & 63)) & 1ull) ? 1.0f : 0.0f;
        float e = __expf((acc[mi][ni][r] - gm) * 0.125f) * in;
        s += e;
        int sbyte = w * 256 + ni * 32 + lo * 2;
        *(unsigned short*)(KP + row * 1024 + (sbyte ^ ((row & 7) << 4))) = f2bf(e);
      }
      #pragma unroll
      for (int xm = 1; xm <= 8; xm <<= 1) s += __shfl_xor(s, xm);
      if (lo == 0) red2[row * 4 + w] = s;
    }
  __syncthreads();
  if (w == 0 && lo == 0) {
    #pragma unroll
    for (int mi = 0; mi < 4; ++mi)
      #pragma unroll
      for (int r = 0; r < 4; ++r) {
        int row = mi * 16 + hi * 4 + r;
        float4 s4 = *(const float4*)&red2[row * 4];
        rnv[row] = 1.0f / ((s4.x + s4.y) + (s4.z + s4.w));
      }
  }
  __syncthreads();
  f32x4 pacc[4] = {};
  for (int kk = 0; kk < 16; ++kk) {
    int rv = w * 16 + lo;
    short8 bv = *(const short8*)(Vd + rv * 1024 + ((kk * 64 + hi * 16) ^ ((rv & 7) << 4)));
    #pragma unroll
    for (int mi = 0; mi < 4; ++mi) {
      int ra = mi * 16 + lo;
      short8 av = *(const short8*)(KP + ra * 1024 + ((kk * 64 + hi * 16) ^ ((ra & 7) << 4)));
      pacc[mi] = __builtin_amdgcn_mfma_f32_16x16x32_bf16(av, bv, pacc[mi], 0, 0, 0);
    }
  }
  #pragma unroll
  for (int mi = 0; mi < 4; ++mi)
    #pragma unroll
    for (int r = 0; r < 4; ++r) {
      int row = mi * 16 + hi * 4 + r;
      ctx[(size_t)(b * II + row) * DD + h * 64 + w * 16 + lo] = f2bf(pacc[mi][r] * rnv[row]);
    }
}

// ---------------- residual + Σ(NP split-K partials) + gemm-bias + LayerNorm ----------------
template <int FINAL, int NP>
__global__ __launch_bounds__(256) void ln_kernel(const float* __restrict__ x, const float* __restrict__ y,
                                                 const float* __restrict__ gb,
                                                 const float* __restrict__ g, const float* __restrict__ bb,
                                                 float* __restrict__ qf, unsigned short* __restrict__ qb,
                                                 const int* __restrict__ zi, const float* __restrict__ zc,
                                                 float* __restrict__ out) {
  __shared__ float r1[4], r2[4];
  const int MN = BB * II * DD;
  int r = blockIdx.x, t = threadIdx.x;
  size_t o = (size_t)r * DD;
  float v0 = x[o + t] + gb[t];
  float v1 = x[o + t + 256] + gb[t + 256];
  float v2 = x[o + t + 512] + gb[t + 512];
  #pragma unroll
  for (int p = 0; p < NP; ++p) {
    size_t po = (size_t)p * MN + o;
    v0 += y[po + t];
    v1 += y[po + t + 256];
    v2 += y[po + t + 512];
  }
  float s = v0 + v1 + v2, ss = v0 * v0 + v1 * v1 + v2 * v2;
  #pragma unroll
  for (int o2 = 32; o2; o2 >>= 1) { s += __shfl_xor(s, o2); ss += __shfl_xor(ss, o2); }
  if ((t & 63) == 0) { r1[t >> 6] = s; r2[t >> 6] = ss; }
  __syncthreads();
  s = r1[0] + r1[1] + r1[2] + r1[3];
  ss = r2[0] + r2[1] + r2[2] + r2[3];
  float mean = s * (1.0f / DD);
  float var = ss * (1.0f / DD) - mean * mean;
  float inv = rsqrtf(var + 1e-12f);
  float w0 = (v0 - mean) * inv * g[t] + bb[t];
  float w1 = (v1 - mean) * inv * g[t + 256] + bb[t + 256];
  float w2 = (v2 - mean) * inv * g[t + 512] + bb[t + 512];
  if (FINAL) {
    int z = zi[r];
    out[o + t] = z ? zc[t] : w0;
    out[o + t + 256] = z ? zc[t + 256] : w1;
    out[o + t + 512] = z ? zc[t + 512] : w2;
  } else {
    qf[o + t] = w0; qf[o + t + 256] = w1; qf[o + t + 512] = w2;
    qb[o + t] = f2bf(w0); qb[o + t + 256] = f2bf(w1); qb[o + t + 512] = f2bf(w2);
  }
}

extern "C" void kernel_launch(void* const* d_in, const int* in_sizes, int n_in,
                              void* d_out, int out_size, void* d_ws, size_t ws_size,
                              hipStream_t stream) {
  (void)in_sizes; (void)n_in; (void)out_size; (void)ws_size;
  const float* hs0 = (const float*)d_in[0];
  const float* hs1 = (const float*)d_in[1];
  const float* Wq  = (const float*)d_in[3];
  const float* bq  = (const float*)d_in[4];
  const float* Wk  = (const float*)d_in[5];
  const float* bk  = (const float*)d_in[6];
  const float* Wv  = (const float*)d_in[7];
  const float* bv  = (const float*)d_in[8];
  const float* Wo  = (const float*)d_in[9];
  const float* bo  = (const float*)d_in[10];
  const float* ln1g = (const float*)d_in[11];
  const float* ln1b = (const float*)d_in[12];
  const float* W1  = (const float*)d_in[13];
  const float* b1  = (const float*)d_in[14];
  const float* W2  = (const float*)d_in[15];
  const float* b2  = (const float*)d_in[16];
  const float* ln2g = (const float*)d_in[17];
  const float* ln2b = (const float*)d_in[18];
  const float* zc  = (const float*)d_in[19];
  const int*   mask = (const int*)d_in[20];

  char* ws = (char*)d_ws;
  size_t off = 0;
  auto alloc = [&](size_t bytes) { size_t o = off; off += (bytes + 255) & ~(size_t)255; return o; };

  unsigned short* WT4 = (unsigned short*)(ws + alloc((size_t)4 * LL * DD * DD * 2));
  unsigned short* W1T = (unsigned short*)(ws + alloc((size_t)LL * FF * DD * 2));
  unsigned short* W2T = (unsigned short*)(ws + alloc((size_t)LL * DD * FF * 2));
  unsigned short* hsb = (unsigned short*)(ws + alloc((size_t)2 * BB * SS * DD * 2));
  float*          qf  = (float*)(ws + alloc((size_t)BB * II * DD * 4));
  float*          qf2 = (float*)(ws + alloc((size_t)BB * II * DD * 4));
  unsigned short* qb  = (unsigned short*)(ws + alloc((size_t)BB * II * DD * 2));
  unsigned short* khb = (unsigned short*)(ws + alloc((size_t)LL * BB * SS * DD * 2));
  unsigned short* vTall = (unsigned short*)(ws + alloc((size_t)LL * DD * BB * SS * 2));
  unsigned short* ctxb = (unsigned short*)(ws + alloc((size_t)BB * II * DD * 2));
  float*          att_o = (float*)(ws + alloc((size_t)2 * BB * II * DD * 4));
  unsigned short* ffh = (unsigned short*)(ws + alloc((size_t)BB * II * FF * 2));
  float*          ffo = (float*)(ws + alloc((size_t)4 * BB * II * DD * 4));
  unsigned long long* pmask = (unsigned long long*)(ws + alloc((size_t)BB * II * 8 * 8));
  int*            zib = (int*)(ws + alloc((size_t)BB * II * 4));

  unsigned short* WqT = WT4 + 0 * (size_t)LL * DD * DD;
  unsigned short* WkT = WT4 + 1 * (size_t)LL * DD * DD;
  unsigned short* WvT = WT4 + 2 * (size_t)LL * DD * DD;
  unsigned short* WoT = WT4 + 3 * (size_t)LL * DD * DD;

  (void)hipFuncSetAttribute((const void*)attn_kernel,
                            hipFuncAttributeMaxDynamicSharedMemorySize, ATTN_LDS);
  (void)hipFuncSetAttribute((const void*)ffn1_kernel,
                            hipFuncAttributeMaxDynamicSharedMemorySize, FFN1_LDS);

  dim3 tb(32, 8);
  TC tc = { { Wq, Wk, Wv, Wo, W1, W2 } };
  tcast_all<<<dim3(96, 24, 12), tb, 0, stream>>>(tc, WT4, W1T, W2T);
  cast2_kernel<<<(BB * SS * DD / 4) / 256, 256, 0, stream>>>(hs0, hs1, hsb, hsb + (size_t)BB * SS * DD);
  pool_kernel<<<dim3(BB * II, 3), 256, 0, stream>>>(hs0, mask, zib, qf, qb, pmask);

  // K + V^T projections for BOTH layers in one launch
  {
    const unsigned short* h0 = hsb;
    const unsigned short* h1 = hsb + (size_t)BB * SS * DD;
    GB gK0 = { h0, WkT, bk, khb, BB * SS, DD, 0 };
    GB gV0 = { WvT, h0, bv, vTall, DD, BB * SS, 1 };
    GB gK1 = { h1, WkT + (size_t)DD * DD, bk + DD, khb + (size_t)BB * SS * DD, BB * SS, DD, 0 };
    GB gV1 = { WvT + (size_t)DD * DD, h1, bv + DD, vTall + (size_t)DD * BB * SS, DD, BB * SS, 1 };
    gemm_nt<0, 1><<<dim3(16, 6, 4), 256, 0, stream>>>(gK0, gV0, gK1, gV1, DD);
  }

  for (int l = 0; l < LL; ++l) {
    const unsigned short* khl = khb + (size_t)l * BB * SS * DD;
    const unsigned short* vTl = vTall + (size_t)l * DD * BB * SS;
    // fused attention (includes Q projection)
    attn_kernel<<<dim3(BB * HH), 256, ATTN_LDS, stream>>>(
        qb, WqT + (size_t)l * DD * DD, bq + l * DD, khl, vTl, pmask, ctxb);
    // Wo projection: split-K=2, fp32 partials
    GB gO = { ctxb, WoT + (size_t)l * DD * DD, nullptr, att_o, BB * II, DD, 0 };
    gemm_sk<0, 0, 1><<<dim3(4, 12, 2), 256, 0, stream>>>(gO, DD, DD / 2);
    // fused LN1 + FFN1 (writes qf2 = LN1 output, ffh = GELU(FFN1))
    ffn1_kernel<<<dim3(4, FF / 64), 256, FFN1_LDS, stream>>>(
        qf, att_o, bo + l * DD, ln1g + l * DD, ln1b + l * DD, qf2,
        W1T + (size_t)l * FF * DD, b1 + l * FF, ffh);
    // FFN2: split-K=4, fp32 partials
    GB gF2 = { ffh, W2T + (size_t)l * DD * FF, nullptr, ffo, BB * II, DD, 0 };
    gemm_sk<0, 0, 1><<<dim3(4, 12, 4), 256, 0, stream>>>(gF2, FF, FF / 4);
    // LN2: residual(qf2) + 4 partials + b2 (layer 1: fused zero-context substitution)
    if (l == 0)
      ln_kernel<0, 4><<<BB * II, 256, 0, stream>>>(qf2, ffo, b2 + l * DD,
                                                   ln2g + l * DD, ln2b + l * DD, qf, qb,
                                                   nullptr, nullptr, nullptr);
    else
      ln_kernel<1, 4><<<BB * II, 256, 0, stream>>>(qf2, ffo, b2 + l * DD,
                                                   ln2g + l * DD, ln2b + l * DD, nullptr, nullptr,
                                                   zib, zc, (float*)d_out);
  }
}